// Round 14
// baseline (436.942 us; speedup 1.0000x reference)
//
#include <hip/hip_runtime.h>
#include <math.h>

// ---------------- weight transpose: w[18][C][3][3] -> wt[C][9][18] ----------------
__global__ void transpose_w_kernel(const float* __restrict__ w, float* __restrict__ wt, int C) {
  int idx = blockIdx.x * blockDim.x + threadIdx.x;
  int total = 18 * C * 9;
  if (idx >= total) return;
  int co = idx / (C * 9);
  int rem = idx % (C * 9);
  int ci = rem / 9;
  int tap = rem % 9;
  wt[(ci * 9 + tap) * 18 + co] = w[idx];
}

// ---------------- fc1 transpose: fc1_w[225][450] -> wt[450][256] (padded) ----------------
__global__ void transpose_fc1_kernel(const float* __restrict__ w, float* __restrict__ wt) {
  int idx = blockIdx.x * blockDim.x + threadIdx.x;
  if (idx >= 225 * 450) return;
  int o = idx / 450;
  int i = idx % 450;
  wt[i * 256 + o] = w[idx];
}

// ------------- uniform-chunk conv3x3 (fv finalized inline; bev -> partials) ------------
// r14 theory: VALUBusy ~= 0.8*Occupancy in all prior configs -> loss is residency
// (grid quantization + mixed durations), not latency. Chunk = 4 splits x 32ci
// (identical cost for bev/fv). 5824 chunks over 2048 persistent blocks (<=3 each),
// 14.6KB LDS -> 8 blocks/CU -> ONE fully-resident round, ~95% packed.
// Inner loop = ROUND-6 VERBATIM (r5/r7/r8/r9: restructure = 2-2.5x regression).
// XCD stripes: block (bid&7) owns chunks [(bid&7)*728, +728) contiguous.
__global__ __launch_bounds__(256) void pre_chunk_kernel(
    const float* __restrict__ xF, const float* __restrict__ wtF,
    const float* __restrict__ b1F, const float* __restrict__ gF,
    const float* __restrict__ beF, const float* __restrict__ muF,
    const float* __restrict__ vF, const float* __restrict__ w2F,
    const float* __restrict__ b2F, float* __restrict__ outF,
    const float* __restrict__ xB, const float* __restrict__ wtB,
    float* __restrict__ partial) {
  int tid = threadIdx.x;
  int pixel = tid & 63;
  int split = __builtin_amdgcn_readfirstlane(tid >> 6);  // wave-uniform -> SGPR

  __shared__ float red[3][64][19];  // pad 19: conflict-free across pixel index

  for (int k = 0; k < 3; ++k) {
    int li = (blockIdx.x >> 3) + k * 256;   // local index in this XCD's stripe
    if (li >= 728) break;                    // block-uniform
    int c = (blockIdx.x & 7) * 728 + li;

    const float *x, *wt;
    int H, W, xt, h, b, cig, C;
    bool isBev;
    if (c < 4800) {  // bev chunk: (3 xt, 200 h, 2 b) x 4 cig
      int rest = c >> 2;
      cig = c & 3;
      xt = rest % 3; h = (rest / 3) % 200; b = rest / 600;
      x = xB; wt = wtB; H = 200; W = 176; C = 512; isBev = true;
    } else {         // fv chunk: (8 xt, 64 h, 2 b)
      int f = c - 4800;
      cig = 0;
      xt = f & 7; h = (f >> 3) & 63; b = f >> 9;
      x = xF; wt = wtF; H = 64; W = 512; C = 128; isBev = false;
    }

    int w = xt * 64 + pixel;
    bool active = (w < W);

    float acc[18];
#pragma unroll
    for (int i = 0; i < 18; i++) acc[i] = 0.f;

    const float* xb = x + (size_t)b * C * H * W;
    int ci0 = cig * 128 + split * 32;
    for (int ci = 0; ci < 32; ci++) {
      const float* plane = xb + (size_t)(ci0 + ci) * H * W;
#pragma unroll
      for (int dh = 0; dh < 3; dh++) {
        int r = h + dh - 1;
        if ((unsigned)r < (unsigned)H) {
          const float* row = plane + (size_t)r * W;
          float v0 = (active && w >= 1) ? row[w - 1] : 0.f;
          float v1 = active ? row[w] : 0.f;
          float v2 = (active && w + 1 < W) ? row[w + 1] : 0.f;
          const float* wp = wt + ((size_t)(ci0 + ci) * 9 + dh * 3) * 18;  // scalar addr
#pragma unroll
          for (int co = 0; co < 18; co++) acc[co] = fmaf(v0, wp[co], acc[co]);
#pragma unroll
          for (int co = 0; co < 18; co++) acc[co] = fmaf(v1, wp[18 + co], acc[co]);
#pragma unroll
          for (int co = 0; co < 18; co++) acc[co] = fmaf(v2, wp[36 + co], acc[co]);
        }
      }
    }

    __syncthreads();  // red reuse across k: previous reads done
    if (split > 0) {
#pragma unroll
      for (int co = 0; co < 18; co++) red[split - 1][pixel][co] = acc[co];
    }
    __syncthreads();
    if (split == 0) {
#pragma unroll
      for (int s = 0; s < 3; s++)
#pragma unroll
        for (int co = 0; co < 18; co++) acc[co] += red[s][pixel][co];
      if (isBev) {
        float* pb = partial + (size_t)c * 1152;  // [18][64]
#pragma unroll
        for (int co = 0; co < 18; co++) pb[co * 64 + pixel] = acc[co];
      } else if (active) {
        float y[18];
#pragma unroll
        for (int co = 0; co < 18; co++) {
          float sc = gF[co] / sqrtf(vF[co] + 1e-3f);
          y[co] = fmaxf((acc[co] + b1F[co] - muF[co]) * sc + beF[co], 0.f);
        }
        size_t obase = (size_t)b * 18 * H * W + (size_t)h * W + w;
#pragma unroll
        for (int co2 = 0; co2 < 18; co2++) {
          float s2 = b2F[co2];
#pragma unroll
          for (int cc = 0; cc < 18; cc++) s2 = fmaf(y[cc], w2F[co2 * 18 + cc], s2);
          outF[obase + (size_t)co2 * H * W] = s2;
        }
      }
    }
  }
}

// ------------- bev: sum 4 partials + BN + relu + 1x1 -------------
__global__ __launch_bounds__(256) void bev_reduce_kernel(
    const float* __restrict__ partial, const float* __restrict__ b1,
    const float* __restrict__ gamma, const float* __restrict__ beta,
    const float* __restrict__ mean, const float* __restrict__ var,
    const float* __restrict__ w2, const float* __restrict__ b2,
    float* __restrict__ out) {
  int idx = blockIdx.x * 256 + threadIdx.x;  // [0, 1200*64)
  if (idx >= 76800) return;
  int pixel = idx & 63;
  int rest = idx >> 6;  // [0,1200) = b*600 + h*3 + xt
  int xt = rest % 3, h = (rest / 3) % 200, b = rest / 600;
  int w = xt * 64 + pixel;
  if (w >= 176) return;
  const float* p0 = partial + (size_t)rest * 4 * 1152;
  float y[18];
#pragma unroll
  for (int co = 0; co < 18; co++) {
    int o = co * 64 + pixel;
    float a = p0[o] + p0[1152 + o] + p0[2304 + o] + p0[3456 + o];
    float sc = gamma[co] / sqrtf(var[co] + 1e-3f);
    y[co] = fmaxf((a + b1[co] - mean[co]) * sc + beta[co], 0.f);
  }
  size_t obase = (size_t)b * 18 * 200 * 176 + (size_t)h * 176 + w;
#pragma unroll
  for (int co2 = 0; co2 < 18; co2++) {
    float s2 = b2[co2];
#pragma unroll
    for (int c = 0; c < 18; c++) s2 = fmaf(y[c], w2[co2 * 18 + c], s2);
    out[obase + (size_t)co2 * 200 * 176] = s2;
  }
}

// ------------- per-ROI classifier: one 256-thread block (4 waves) per ROI -------------
// All dotted LDS rows padded to stride 28 floats (112B = 7x16B) and read as float4.
__global__ __launch_bounds__(256) void classifier_kernel(
    const float* __restrict__ ffv, const float* __restrict__ fbev,
    const float* __restrict__ rois, const float* __restrict__ Wq,
    const float* __restrict__ bq, const float* __restrict__ Wk,
    const float* __restrict__ bk, const float* __restrict__ Wv,
    const float* __restrict__ bv, const float* __restrict__ Wf,
    const float* __restrict__ bf, const float* __restrict__ conv_w,
    const float* __restrict__ conv_b, const float* __restrict__ wt_fc1,
    const float* __restrict__ fc1_b, const float* __restrict__ fc2_w,
    const float* __restrict__ fc2_b, float* __restrict__ out) {
  int rid = blockIdx.x;
  int b = rid >> 10;
  int tid = threadIdx.x;

  __shared__ __align__(16) float sW[4 * 25 * 28];   // q|k|v|f rows, padded
  __shared__ float sB[100];                          // bq | bk | bv | bf
  __shared__ __align__(16) float sfv[18 * 28], sbev[18 * 28];
  __shared__ __align__(16) float pr[6 * 18 * 28];    // qf kf vf qb kb vb
  __shared__ __align__(16) float av[2 * 18 * 28];
  __shared__ __align__(16) float xx[2 * 18 * 28];
  __shared__ __align__(16) float hid[452];
  __shared__ float h1r[226];
  __shared__ float lg[3];
  __shared__ int c_ixf[25], c_iyf[25], c_vf[25];
  __shared__ int c_ixb[25], c_iyb[25], c_vb[25];

  // ---- stage projection weights + biases into LDS (padded rows) ----
  for (int t = tid; t < 625; t += 256) {
    int j = t / 25, i = t % 25;
    sW[(0 * 25 + j) * 28 + i] = Wq[t];
    sW[(1 * 25 + j) * 28 + i] = Wk[t];
    sW[(2 * 25 + j) * 28 + i] = Wv[t];
    sW[(3 * 25 + j) * 28 + i] = Wf[t];
  }
  if (tid < 25) {
    sB[tid] = bq[tid];
    sB[25 + tid] = bk[tid];
    sB[50 + tid] = bv[tid];
    sB[75 + tid] = bf[tid];
  }

  // ---- box + grids coords (double to match np f64 ref) ----
  if (tid < 25) {
    const float* roi = rois + (size_t)rid * 7;
    double x0 = roi[0], y0 = roi[1], z0 = roi[2];
    double dx = roi[3], dy = roi[4], dz = roi[5], th = roi[6];
    double c = cos(th), s = sin(th);
    double half1 = (dy * c + dx * s) / 2.0;
    double half2 = (dy * s + dx * c) / 2.0;
    double bx1 = x0 - half1, bx2 = x0 + half1;
    double by1 = y0 - half2, by2 = y0 + half2;
    double bz1 = z0 - dz / 2.0, bz2 = z0 + dz / 2.0;
    int i = tid / 5, j = tid % 5;
    double ti = i * 0.25, tj = j * 0.25;
    // fv: feat (18, 64, 512)
    double gz = bz1 + ti * (bz2 - bz1);
    gz = (gz + 1.0) / 2.0;
    double gx = bx1 + tj * (bx2 - bx1);
    gx = (gx - 35.2) / 35.2;
    double ixf = rint((gz + 1.0) * 0.5 * 511.0);
    double iyf = rint((gx + 1.0) * 0.5 * 63.0);
    c_vf[tid] = (ixf >= 0.0) && (ixf <= 511.0) && (iyf >= 0.0) && (iyf <= 63.0);
    c_ixf[tid] = (int)fmin(fmax(ixf, 0.0), 511.0);
    c_iyf[tid] = (int)fmin(fmax(iyf, 0.0), 63.0);
    // bev: feat (18, 200, 176)
    double gzb = (by1 + ti * (by2 - by1)) / 40.0;
    double ixb = rint((gzb + 1.0) * 0.5 * 175.0);
    double iyb = rint((gx + 1.0) * 0.5 * 199.0);
    c_vb[tid] = (ixb >= 0.0) && (ixb <= 175.0) && (iyb >= 0.0) && (iyb <= 199.0);
    c_ixb[tid] = (int)fmin(fmax(ixb, 0.0), 175.0);
    c_iyb[tid] = (int)fmin(fmax(iyb, 0.0), 199.0);
  }
  __syncthreads();

  // ---- gather: 900 items (450 fv + 450 bev) across 256 threads ----
  {
    const float* fvb = ffv + (size_t)b * 18 * 64 * 512;
    const float* bvb = fbev + (size_t)b * 18 * 200 * 176;
    for (int item = tid; item < 900; item += 256) {
      if (item < 450) {
        int ch = item / 25, pos = item % 25;
        sfv[ch * 28 + pos] = c_vf[pos] ? fvb[((size_t)ch * 64 + c_iyf[pos]) * 512 + c_ixf[pos]] : 0.f;
      } else {
        int it = item - 450;
        int ch = it / 25, pos = it % 25;
        sbev[ch * 28 + pos] = c_vb[pos] ? bvb[((size_t)ch * 200 + c_iyb[pos]) * 176 + c_ixb[pos]] : 0.f;
      }
    }
  }
  __syncthreads();

  // ---- 6 projections: {fv,bev} x {Wq,Wk,Wv}, float4 LDS reads ----
  for (int idx = tid; idx < 450; idx += 256) {
    int t = idx / 25, j = idx % 25;
    const float4* xa4 = (const float4*)(sfv + t * 28);
    const float4* xb4 = (const float4*)(sbev + t * 28);
    const float4* wq4 = (const float4*)(sW + (0 * 25 + j) * 28);
    const float4* wk4 = (const float4*)(sW + (1 * 25 + j) * 28);
    const float4* wv4 = (const float4*)(sW + (2 * 25 + j) * 28);
    float aqf = sB[j], akf = sB[25 + j], avf = sB[50 + j];
    float aqb = sB[j], akb = sB[25 + j], avb = sB[50 + j];
#pragma unroll
    for (int k = 0; k < 6; k++) {  // elements 0..23
      float4 xa = xa4[k], xb = xb4[k];
      float4 wq = wq4[k], wk = wk4[k], wv = wv4[k];
      aqf = fmaf(xa.w, wq.w, fmaf(xa.z, wq.z, fmaf(xa.y, wq.y, fmaf(xa.x, wq.x, aqf))));
      akf = fmaf(xa.w, wk.w, fmaf(xa.z, wk.z, fmaf(xa.y, wk.y, fmaf(xa.x, wk.x, akf))));
      avf = fmaf(xa.w, wv.w, fmaf(xa.z, wv.z, fmaf(xa.y, wv.y, fmaf(xa.x, wv.x, avf))));
      aqb = fmaf(xb.w, wq.w, fmaf(xb.z, wq.z, fmaf(xb.y, wq.y, fmaf(xb.x, wq.x, aqb))));
      akb = fmaf(xb.w, wk.w, fmaf(xb.z, wk.z, fmaf(xb.y, wk.y, fmaf(xb.x, wk.x, akb))));
      avb = fmaf(xb.w, wv.w, fmaf(xb.z, wv.z, fmaf(xb.y, wv.y, fmaf(xb.x, wv.x, avb))));
    }
    {  // element 24
      float xa = sfv[t * 28 + 24], xb = sbev[t * 28 + 24];
      float wq = sW[(0 * 25 + j) * 28 + 24], wk = sW[(1 * 25 + j) * 28 + 24],
            wv = sW[(2 * 25 + j) * 28 + 24];
      aqf = fmaf(xa, wq, aqf); akf = fmaf(xa, wk, akf); avf = fmaf(xa, wv, avf);
      aqb = fmaf(xb, wq, aqb); akb = fmaf(xb, wk, akb); avb = fmaf(xb, wv, avb);
    }
    pr[(0 * 18 + t) * 28 + j] = aqf;
    pr[(1 * 18 + t) * 28 + j] = akf;
    pr[(2 * 18 + t) * 28 + j] = avf;
    pr[(3 * 18 + t) * 28 + j] = aqb;
    pr[(4 * 18 + t) * 28 + j] = akb;
    pr[(5 * 18 + t) * 28 + j] = avb;
  }
  __syncthreads();

  // ---- attention (both mhsa): row = (head, token), 90 rows (scalar LDS, stride 28) ----
  const float rs5 = 0.44721359549995793f;  // 1/sqrt(5)
  if (tid < 90) {
    int hh = tid / 18, t = tid % 18;
#pragma unroll
    for (int m = 0; m < 2; m++) {
      const float* q = pr + (m == 0 ? 0 : 3) * 18 * 28;
      const float* k = pr + (m == 0 ? 4 : 1) * 18 * 28;
      const float* v = pr + (m == 0 ? 2 : 5) * 18 * 28;
      float p_[18];
      float mx = -1e30f;
#pragma unroll
      for (int ss = 0; ss < 18; ss++) {
        float sc = 0.f;
#pragma unroll
        for (int d = 0; d < 5; d++)
          sc = fmaf(q[t * 28 + hh * 5 + d], k[ss * 28 + hh * 5 + d], sc);
        sc *= rs5;
        p_[ss] = sc;
        mx = fmaxf(mx, sc);
      }
      float sm = 0.f;
#pragma unroll
      for (int ss = 0; ss < 18; ss++) {
        p_[ss] = expf(p_[ss] - mx);
        sm += p_[ss];
      }
      float inv = 1.f / sm;
#pragma unroll
      for (int d = 0; d < 5; d++) {
        float a = 0.f;
#pragma unroll
        for (int ss = 0; ss < 18; ss++)
          a = fmaf(p_[ss], v[ss * 28 + hh * 5 + d], a);
        av[(m * 18 + t) * 28 + hh * 5 + d] = a * inv;
      }
    }
  }
  __syncthreads();

  // ---- out-proj + residual (Wf row + av rows via float4) ----
  for (int idx = tid; idx < 450; idx += 256) {
    int t = idx / 25, j = idx % 25;
    const float4* wf4 = (const float4*)(sW + (3 * 25 + j) * 28);
    const float4* a04 = (const float4*)(av + (0 * 18 + t) * 28);
    const float4* a14 = (const float4*)(av + (1 * 18 + t) * 28);
    float s1 = sB[75 + j] + sbev[t * 28 + j];  // x1 residual = bev (feat1)
    float s2 = sB[75 + j] + sfv[t * 28 + j];   // x2 residual = fv
#pragma unroll
    for (int k = 0; k < 6; k++) {
      float4 wf = wf4[k], a0 = a04[k], a1 = a14[k];
      s1 = fmaf(a0.w, wf.w, fmaf(a0.z, wf.z, fmaf(a0.y, wf.y, fmaf(a0.x, wf.x, s1))));
      s2 = fmaf(a1.w, wf.w, fmaf(a1.z, wf.z, fmaf(a1.y, wf.y, fmaf(a1.x, wf.x, s2))));
    }
    {
      float wf = sW[(3 * 25 + j) * 28 + 24];
      s1 = fmaf(av[(0 * 18 + t) * 28 + 24], wf, s1);
      s2 = fmaf(av[(1 * 18 + t) * 28 + 24], wf, s2);
    }
    xx[(0 * 18 + t) * 28 + j] = s1;
    xx[(1 * 18 + t) * 28 + j] = s2;
  }
  __syncthreads();

  // ---- conv 36->18, 3x3, pad 1 on 5x5 ----
  for (int idx = tid; idx < 450; idx += 256) {
    int co = idx / 25, pos = idx % 25, pi = pos / 5, pj = pos % 5;
    float acc = conv_b[co];
    for (int ci = 0; ci < 36; ci++) {
      const float* xc = (ci < 18) ? &xx[(0 * 18 + ci) * 28] : &xx[(1 * 18 + (ci - 18)) * 28];
      const float* wp = conv_w + ((size_t)co * 36 + ci) * 9;
#pragma unroll
      for (int dh = 0; dh < 3; dh++) {
        int rr = pi + dh - 1;
        if ((unsigned)rr < 5u) {
#pragma unroll
          for (int dw = 0; dw < 3; dw++) {
            int cc = pj + dw - 1;
            if ((unsigned)cc < 5u) acc = fmaf(xc[rr * 5 + cc], wp[dh * 3 + dw], acc);
          }
        }
      }
    }
    hid[idx] = acc;
  }
  __syncthreads();

  // ---- fc1 (225 x 450) + relu: thread t owns output o=t; wt_fc1[i][o] coalesced;
  // hid via float4 (112 x b128 + 2 scalars) ----
  if (tid < 225) {
    int o = tid;
    float a0 = fc1_b[o], a1 = 0.f, a2 = 0.f, a3 = 0.f;
    const float4* h4 = (const float4*)hid;
    for (int k = 0; k < 112; k++) {  // elements 0..447
      float4 hv = h4[k];
      int i = k * 4;
      a0 = fmaf(hv.x, wt_fc1[(size_t)i * 256 + o], a0);
      a1 = fmaf(hv.y, wt_fc1[(size_t)(i + 1) * 256 + o], a1);
      a2 = fmaf(hv.z, wt_fc1[(size_t)(i + 2) * 256 + o], a2);
      a3 = fmaf(hv.w, wt_fc1[(size_t)(i + 3) * 256 + o], a3);
    }
    a0 = fmaf(hid[448], wt_fc1[(size_t)448 * 256 + o], a0);
    a1 = fmaf(hid[449], wt_fc1[(size_t)449 * 256 + o], a1);
    h1r[o] = fmaxf((a0 + a1) + (a2 + a3), 0.f);
  }
  __syncthreads();

  // ---- fc2 (3 x 225): wave w computes output w via shuffle reduction ----
  int wave = tid >> 6, lane = tid & 63;
  if (wave < 3) {
    const float* wr = fc2_w + (size_t)wave * 225;
    float p = 0.f;
#pragma unroll
    for (int k = 0; k < 4; k++) {
      int i = lane + k * 64;
      if (i < 225) p = fmaf(h1r[i], wr[i], p);
    }
#pragma unroll
    for (int m = 32; m >= 1; m >>= 1) p += __shfl_xor(p, m);
    if (lane == 0) lg[wave] = p + fc2_b[wave];
  }
  __syncthreads();

  // ---- argmax + softmax ----
  if (tid == 0) {
    float l0 = lg[0], l1 = lg[1], l2 = lg[2];
    int arg = 0;
    float bm = l0;
    if (l1 > bm) { arg = 1; bm = l1; }
    if (l2 > bm) { arg = 2; bm = l2; }
    float m = fmaxf(l0, fmaxf(l1, l2));
    float e0 = expf(l0 - m), e1 = expf(l1 - m), e2 = expf(l2 - m);
    float inv = 1.f / (e0 + e1 + e2);
    out[rid] = (float)(arg + 1);
    float* sc = out + 2048 + (size_t)rid * 3;
    sc[0] = e0 * inv;
    sc[1] = e1 * inv;
    sc[2] = e2 * inv;
  }
}

extern "C" void kernel_launch(void* const* d_in, const int* in_sizes, int n_in,
                              void* d_out, int out_size, void* d_ws, size_t ws_size,
                              hipStream_t stream) {
  const float* feat_fv = (const float*)d_in[0];
  const float* feat_bev = (const float*)d_in[1];
  const float* rois = (const float*)d_in[2];
  const float* fv_w1 = (const float*)d_in[3];
  const float* fv_b1 = (const float*)d_in[4];
  const float* fv_gamma = (const float*)d_in[5];
  const float* fv_beta = (const float*)d_in[6];
  const float* fv_mean = (const float*)d_in[7];
  const float* fv_var = (const float*)d_in[8];
  const float* fv_w2 = (const float*)d_in[9];
  const float* fv_b2 = (const float*)d_in[10];
  const float* bev_w1 = (const float*)d_in[11];
  const float* bev_b1 = (const float*)d_in[12];
  const float* bev_gamma = (const float*)d_in[13];
  const float* bev_beta = (const float*)d_in[14];
  const float* bev_mean = (const float*)d_in[15];
  const float* bev_var = (const float*)d_in[16];
  const float* bev_w2 = (const float*)d_in[17];
  const float* bev_b2 = (const float*)d_in[18];
  const float* Wq = (const float*)d_in[19];
  const float* bq = (const float*)d_in[20];
  const float* Wk = (const float*)d_in[21];
  const float* bk = (const float*)d_in[22];
  const float* Wv = (const float*)d_in[23];
  const float* bv = (const float*)d_in[24];
  const float* Wf = (const float*)d_in[25];
  const float* bf = (const float*)d_in[26];
  const float* conv_w = (const float*)d_in[27];
  const float* conv_b = (const float*)d_in[28];
  const float* fc1_w = (const float*)d_in[29];
  const float* fc1_b = (const float*)d_in[30];
  const float* fc2_w = (const float*)d_in[31];
  const float* fc2_b = (const float*)d_in[32];

  float* ws = (float*)d_ws;
  float* ffv = ws;                       // 2*18*64*512  = 1,179,648 floats
  float* fbev = ffv + 1179648;           // 2*18*200*176 = 1,267,200 floats
  float* wt_fv = fbev + 1267200;         // 128*9*18     = 20,736
  float* wt_bev = wt_fv + 20736;         // 512*9*18     = 82,944
  float* wt_fc1 = wt_bev + 82944;        // 450*256      = 115,200
  float* partial = wt_fc1 + 115200;      // 4800*1152    = 5,529,600 (~22MB)
  // total ~33MB

  transpose_w_kernel<<<(18 * 128 * 9 + 255) / 256, 256, 0, stream>>>(fv_w1, wt_fv, 128);
  transpose_w_kernel<<<(18 * 512 * 9 + 255) / 256, 256, 0, stream>>>(bev_w1, wt_bev, 512);
  transpose_fc1_kernel<<<(225 * 450 + 255) / 256, 256, 0, stream>>>(fc1_w, wt_fc1);

  // uniform chunks: 4800 bev (write partials) + 1024 fv (finalize inline),
  // 2048 persistent blocks x <=3 chunks, XCD-striped
  pre_chunk_kernel<<<2048, 256, 0, stream>>>(
      feat_fv, wt_fv, fv_b1, fv_gamma, fv_beta, fv_mean, fv_var, fv_w2, fv_b2, ffv,
      feat_bev, wt_bev, partial);

  bev_reduce_kernel<<<300, 256, 0, stream>>>(
      partial, bev_b1, bev_gamma, bev_beta, bev_mean, bev_var, bev_w2, bev_b2, fbev);

  classifier_kernel<<<2048, 256, 0, stream>>>(
      ffv, fbev, rois, Wq, bq, Wk, bk, Wv, bv, Wf, bf, conv_w, conv_b, wt_fc1,
      fc1_b, fc2_w, fc2_b, (float*)d_out);
}

// Round 16
// 390.933 us; speedup vs baseline: 1.1177x; 1.1177x over previous
//
#include <hip/hip_runtime.h>
#include <math.h>

// ---------------- weight transpose: w[18][C][3][3] -> wt[C][9][18] ----------------
__global__ void transpose_w_kernel(const float* __restrict__ w, float* __restrict__ wt, int C) {
  int idx = blockIdx.x * blockDim.x + threadIdx.x;
  int total = 18 * C * 9;
  if (idx >= total) return;
  int co = idx / (C * 9);
  int rem = idx % (C * 9);
  int ci = rem / 9;
  int tap = rem % 9;
  wt[(ci * 9 + tap) * 18 + co] = w[idx];
}

// ---------------- fc1 transpose: fc1_w[225][450] -> wt[450][256] (padded) ----------------
__global__ void transpose_fc1_kernel(const float* __restrict__ w, float* __restrict__ wt) {
  int idx = blockIdx.x * blockDim.x + threadIdx.x;
  if (idx >= 225 * 450) return;
  int o = idx / 450;
  int i = idx % 450;
  wt[i * 256 + o] = w[idx];
}

// ------------- merged fused conv3x3 + BN + relu + conv1x1 (fv + bev in one grid) ------------
// Body facts established r5..r14: 54-weight FMA batches + row_base+{w-1,w,w+1} taps is the
// only codegen-safe loop shape; total VALU cycles are invariant (~128us); duration = f(duty,
// residency). Duty cap traced to SMEM weight-stall (54 live weight SGPRs of 112 -> no
// prefetch). r12 proved dual-row (2x FMA per weight batch) keeps codegen intact; r13 proved
// 512-thr/8-split keeps codegen intact. This kernel combines them: 1112 blocks x 8 waves,
// rows (h,h+1) per thread, two-phase LDS reduction (34KB -> 4 blocks/CU at thread cap).
__global__ __launch_bounds__(512) void pre_merged_kernel(
    const float* __restrict__ xF, const float* __restrict__ wtF,
    const float* __restrict__ b1F, const float* __restrict__ gF,
    const float* __restrict__ beF, const float* __restrict__ muF,
    const float* __restrict__ vF, const float* __restrict__ w2F,
    const float* __restrict__ b2F, float* __restrict__ outF,
    const float* __restrict__ xB, const float* __restrict__ wtB,
    const float* __restrict__ b1B, const float* __restrict__ gB,
    const float* __restrict__ beB, const float* __restrict__ muB,
    const float* __restrict__ vB, const float* __restrict__ w2B,
    const float* __restrict__ b2B, float* __restrict__ outB) {
  int orig = blockIdx.x;
  int flat;
  if (orig < 600) {                        // bev: 600 = 8 XCD x 75
    flat = (orig & 7) * 75 + (orig >> 3);
  } else {                                 // fv: 512 = 8 XCD x 64 (600%8==0)
    int j = orig - 600;
    flat = 600 + (j & 7) * 64 + (j >> 3);
  }

  const float *x, *wt, *b1, *gamma, *beta, *mean, *var, *w2, *b2;
  float* out;
  int H, W, cs, xt, h, b;
  if (flat < 600) {   // bev: (3 xt, 100 h-pairs, 2 b), C=512, cs=64, rows (h, h+1)
    xt = flat % 3; h = 2 * ((flat / 3) % 100); b = flat / 300;
    x = xB; wt = wtB; b1 = b1B; gamma = gB; beta = beB; mean = muB; var = vB;
    w2 = w2B; b2 = b2B; out = outB;
    H = 200; W = 176; cs = 64;
  } else {            // fv: (8 xt, 32 h-pairs, 2 b), C=128, cs=16, rows (h, h+1)
    int f = flat - 600;
    xt = f & 7; h = 2 * ((f >> 3) & 31); b = f >> 8;
    x = xF; wt = wtF; b1 = b1F; gamma = gF; beta = beF; mean = muF; var = vF;
    w2 = w2F; b2 = b2F; out = outF;
    H = 64; W = 512; cs = 16;
  }

  int tid = threadIdx.x;
  int pixel = tid & 63;
  int split = __builtin_amdgcn_readfirstlane(tid >> 6);  // wave-uniform -> SGPR
  int w = xt * 64 + pixel;
  bool active = (w < W);

  float acc[18], acc2[18];
#pragma unroll
  for (int i = 0; i < 18; i++) { acc[i] = 0.f; acc2[i] = 0.f; }

  const float* xb = x + (size_t)b * (cs * 8) * H * W;
  int ci0 = split * cs;
  for (int ci = 0; ci < cs; ci++) {
    const float* plane = xb + (size_t)(ci0 + ci) * H * W;
#pragma unroll
    for (int dh = 0; dh < 3; dh++) {
      const float* wp = wt + ((size_t)(ci0 + ci) * 9 + dh * 3) * 18;  // scalar addr
      int r = h + dh - 1;
      if ((unsigned)r < (unsigned)H) {
        const float* row = plane + (size_t)r * W;
        float v0 = (active && w >= 1) ? row[w - 1] : 0.f;
        float v1 = active ? row[w] : 0.f;
        float v2 = (active && w + 1 < W) ? row[w + 1] : 0.f;
#pragma unroll
        for (int co = 0; co < 18; co++) acc[co] = fmaf(v0, wp[co], acc[co]);
#pragma unroll
        for (int co = 0; co < 18; co++) acc[co] = fmaf(v1, wp[18 + co], acc[co]);
#pragma unroll
        for (int co = 0; co < 18; co++) acc[co] = fmaf(v2, wp[36 + co], acc[co]);
      }
      int r2 = h + dh;  // second output row h+1 shares this weight batch
      if ((unsigned)r2 < (unsigned)H) {
        const float* row2 = plane + (size_t)r2 * W;
        float u0 = (active && w >= 1) ? row2[w - 1] : 0.f;
        float u1 = active ? row2[w] : 0.f;
        float u2 = (active && w + 1 < W) ? row2[w + 1] : 0.f;
#pragma unroll
        for (int co = 0; co < 18; co++) acc2[co] = fmaf(u0, wp[co], acc2[co]);
#pragma unroll
        for (int co = 0; co < 18; co++) acc2[co] = fmaf(u1, wp[18 + co], acc2[co]);
#pragma unroll
        for (int co = 0; co < 18; co++) acc2[co] = fmaf(u2, wp[36 + co], acc2[co]);
      }
    }
  }

  __shared__ float red[7][64][19];  // 34KB; reused across 2 phases

  // ---- phase A: reduce + finalize row h ----
  if (split > 0) {
#pragma unroll
    for (int co = 0; co < 18; co++) red[split - 1][pixel][co] = acc[co];
  }
  __syncthreads();
  if (split == 0 && active) {
#pragma unroll
    for (int s = 0; s < 7; s++)
#pragma unroll
      for (int co = 0; co < 18; co++) acc[co] += red[s][pixel][co];
    float y[18];
#pragma unroll
    for (int co = 0; co < 18; co++) {
      float sc = gamma[co] / sqrtf(var[co] + 1e-3f);
      y[co] = fmaxf((acc[co] + b1[co] - mean[co]) * sc + beta[co], 0.f);
    }
    size_t obase = (size_t)b * 18 * H * W + (size_t)h * W + w;
#pragma unroll
    for (int co2 = 0; co2 < 18; co2++) {
      float s2 = b2[co2];
#pragma unroll
      for (int c = 0; c < 18; c++) s2 = fmaf(y[c], w2[co2 * 18 + c], s2);
      out[obase + (size_t)co2 * H * W] = s2;
    }
  }
  __syncthreads();

  // ---- phase B: reduce + finalize row h+1 ----
  if (split > 0) {
#pragma unroll
    for (int co = 0; co < 18; co++) red[split - 1][pixel][co] = acc2[co];
  }
  __syncthreads();
  if (split == 0 && active) {
#pragma unroll
    for (int s = 0; s < 7; s++)
#pragma unroll
      for (int co = 0; co < 18; co++) acc2[co] += red[s][pixel][co];
    float y[18];
#pragma unroll
    for (int co = 0; co < 18; co++) {
      float sc = gamma[co] / sqrtf(var[co] + 1e-3f);
      y[co] = fmaxf((acc2[co] + b1[co] - mean[co]) * sc + beta[co], 0.f);
    }
    size_t obase = (size_t)b * 18 * H * W + (size_t)(h + 1) * W + w;
#pragma unroll
    for (int co2 = 0; co2 < 18; co2++) {
      float s2 = b2[co2];
#pragma unroll
      for (int c = 0; c < 18; c++) s2 = fmaf(y[c], w2[co2 * 18 + c], s2);
      out[obase + (size_t)co2 * H * W] = s2;
    }
  }
}

// ------------- per-ROI classifier: one 256-thread block (4 waves) per ROI -------------
// All dotted LDS rows padded to stride 28 floats (112B = 7x16B) and read as float4.
__global__ __launch_bounds__(256) void classifier_kernel(
    const float* __restrict__ ffv, const float* __restrict__ fbev,
    const float* __restrict__ rois, const float* __restrict__ Wq,
    const float* __restrict__ bq, const float* __restrict__ Wk,
    const float* __restrict__ bk, const float* __restrict__ Wv,
    const float* __restrict__ bv, const float* __restrict__ Wf,
    const float* __restrict__ bf, const float* __restrict__ conv_w,
    const float* __restrict__ conv_b, const float* __restrict__ wt_fc1,
    const float* __restrict__ fc1_b, const float* __restrict__ fc2_w,
    const float* __restrict__ fc2_b, float* __restrict__ out) {
  int rid = blockIdx.x;
  int b = rid >> 10;
  int tid = threadIdx.x;

  __shared__ __align__(16) float sW[4 * 25 * 28];   // q|k|v|f rows, padded
  __shared__ float sB[100];                          // bq | bk | bv | bf
  __shared__ __align__(16) float sfv[18 * 28], sbev[18 * 28];
  __shared__ __align__(16) float pr[6 * 18 * 28];    // qf kf vf qb kb vb
  __shared__ __align__(16) float av[2 * 18 * 28];
  __shared__ __align__(16) float xx[2 * 18 * 28];
  __shared__ __align__(16) float hid[452];
  __shared__ float h1r[226];
  __shared__ float lg[3];
  __shared__ int c_ixf[25], c_iyf[25], c_vf[25];
  __shared__ int c_ixb[25], c_iyb[25], c_vb[25];

  // ---- stage projection weights + biases into LDS (padded rows) ----
  for (int t = tid; t < 625; t += 256) {
    int j = t / 25, i = t % 25;
    sW[(0 * 25 + j) * 28 + i] = Wq[t];
    sW[(1 * 25 + j) * 28 + i] = Wk[t];
    sW[(2 * 25 + j) * 28 + i] = Wv[t];
    sW[(3 * 25 + j) * 28 + i] = Wf[t];
  }
  if (tid < 25) {
    sB[tid] = bq[tid];
    sB[25 + tid] = bk[tid];
    sB[50 + tid] = bv[tid];
    sB[75 + tid] = bf[tid];
  }

  // ---- box + grids coords (double to match np f64 ref) ----
  if (tid < 25) {
    const float* roi = rois + (size_t)rid * 7;
    double x0 = roi[0], y0 = roi[1], z0 = roi[2];
    double dx = roi[3], dy = roi[4], dz = roi[5], th = roi[6];
    double c = cos(th), s = sin(th);
    double half1 = (dy * c + dx * s) / 2.0;
    double half2 = (dy * s + dx * c) / 2.0;
    double bx1 = x0 - half1, bx2 = x0 + half1;
    double by1 = y0 - half2, by2 = y0 + half2;
    double bz1 = z0 - dz / 2.0, bz2 = z0 + dz / 2.0;
    int i = tid / 5, j = tid % 5;
    double ti = i * 0.25, tj = j * 0.25;
    // fv: feat (18, 64, 512)
    double gz = bz1 + ti * (bz2 - bz1);
    gz = (gz + 1.0) / 2.0;
    double gx = bx1 + tj * (bx2 - bx1);
    gx = (gx - 35.2) / 35.2;
    double ixf = rint((gz + 1.0) * 0.5 * 511.0);
    double iyf = rint((gx + 1.0) * 0.5 * 63.0);
    c_vf[tid] = (ixf >= 0.0) && (ixf <= 511.0) && (iyf >= 0.0) && (iyf <= 63.0);
    c_ixf[tid] = (int)fmin(fmax(ixf, 0.0), 511.0);
    c_iyf[tid] = (int)fmin(fmax(iyf, 0.0), 63.0);
    // bev: feat (18, 200, 176)
    double gzb = (by1 + ti * (by2 - by1)) / 40.0;
    double ixb = rint((gzb + 1.0) * 0.5 * 175.0);
    double iyb = rint((gx + 1.0) * 0.5 * 199.0);
    c_vb[tid] = (ixb >= 0.0) && (ixb <= 175.0) && (iyb >= 0.0) && (iyb <= 199.0);
    c_ixb[tid] = (int)fmin(fmax(ixb, 0.0), 175.0);
    c_iyb[tid] = (int)fmin(fmax(iyb, 0.0), 199.0);
  }
  __syncthreads();

  // ---- gather: 900 items (450 fv + 450 bev) across 256 threads ----
  {
    const float* fvb = ffv + (size_t)b * 18 * 64 * 512;
    const float* bvb = fbev + (size_t)b * 18 * 200 * 176;
    for (int item = tid; item < 900; item += 256) {
      if (item < 450) {
        int ch = item / 25, pos = item % 25;
        sfv[ch * 28 + pos] = c_vf[pos] ? fvb[((size_t)ch * 64 + c_iyf[pos]) * 512 + c_ixf[pos]] : 0.f;
      } else {
        int it = item - 450;
        int ch = it / 25, pos = it % 25;
        sbev[ch * 28 + pos] = c_vb[pos] ? bvb[((size_t)ch * 200 + c_iyb[pos]) * 176 + c_ixb[pos]] : 0.f;
      }
    }
  }
  __syncthreads();

  // ---- 6 projections: {fv,bev} x {Wq,Wk,Wv}, float4 LDS reads ----
  for (int idx = tid; idx < 450; idx += 256) {
    int t = idx / 25, j = idx % 25;
    const float4* xa4 = (const float4*)(sfv + t * 28);
    const float4* xb4 = (const float4*)(sbev + t * 28);
    const float4* wq4 = (const float4*)(sW + (0 * 25 + j) * 28);
    const float4* wk4 = (const float4*)(sW + (1 * 25 + j) * 28);
    const float4* wv4 = (const float4*)(sW + (2 * 25 + j) * 28);
    float aqf = sB[j], akf = sB[25 + j], avf = sB[50 + j];
    float aqb = sB[j], akb = sB[25 + j], avb = sB[50 + j];
#pragma unroll
    for (int k = 0; k < 6; k++) {  // elements 0..23
      float4 xa = xa4[k], xb = xb4[k];
      float4 wq = wq4[k], wk = wk4[k], wv = wv4[k];
      aqf = fmaf(xa.w, wq.w, fmaf(xa.z, wq.z, fmaf(xa.y, wq.y, fmaf(xa.x, wq.x, aqf))));
      akf = fmaf(xa.w, wk.w, fmaf(xa.z, wk.z, fmaf(xa.y, wk.y, fmaf(xa.x, wk.x, akf))));
      avf = fmaf(xa.w, wv.w, fmaf(xa.z, wv.z, fmaf(xa.y, wv.y, fmaf(xa.x, wv.x, avf))));
      aqb = fmaf(xb.w, wq.w, fmaf(xb.z, wq.z, fmaf(xb.y, wq.y, fmaf(xb.x, wq.x, aqb))));
      akb = fmaf(xb.w, wk.w, fmaf(xb.z, wk.z, fmaf(xb.y, wk.y, fmaf(xb.x, wk.x, akb))));
      avb = fmaf(xb.w, wv.w, fmaf(xb.z, wv.z, fmaf(xb.y, wv.y, fmaf(xb.x, wv.x, avb))));
    }
    {  // element 24
      float xa = sfv[t * 28 + 24], xb = sbev[t * 28 + 24];
      float wq = sW[(0 * 25 + j) * 28 + 24], wk = sW[(1 * 25 + j) * 28 + 24],
            wv = sW[(2 * 25 + j) * 28 + 24];
      aqf = fmaf(xa, wq, aqf); akf = fmaf(xa, wk, akf); avf = fmaf(xa, wv, avf);
      aqb = fmaf(xb, wq, aqb); akb = fmaf(xb, wk, akb); avb = fmaf(xb, wv, avb);
    }
    pr[(0 * 18 + t) * 28 + j] = aqf;
    pr[(1 * 18 + t) * 28 + j] = akf;
    pr[(2 * 18 + t) * 28 + j] = avf;
    pr[(3 * 18 + t) * 28 + j] = aqb;
    pr[(4 * 18 + t) * 28 + j] = akb;
    pr[(5 * 18 + t) * 28 + j] = avb;
  }
  __syncthreads();

  // ---- attention (both mhsa): row = (head, token), 90 rows (scalar LDS, stride 28) ----
  const float rs5 = 0.44721359549995793f;  // 1/sqrt(5)
  if (tid < 90) {
    int hh = tid / 18, t = tid % 18;
#pragma unroll
    for (int m = 0; m < 2; m++) {
      const float* q = pr + (m == 0 ? 0 : 3) * 18 * 28;
      const float* k = pr + (m == 0 ? 4 : 1) * 18 * 28;
      const float* v = pr + (m == 0 ? 2 : 5) * 18 * 28;
      float p_[18];
      float mx = -1e30f;
#pragma unroll
      for (int ss = 0; ss < 18; ss++) {
        float sc = 0.f;
#pragma unroll
        for (int d = 0; d < 5; d++)
          sc = fmaf(q[t * 28 + hh * 5 + d], k[ss * 28 + hh * 5 + d], sc);
        sc *= rs5;
        p_[ss] = sc;
        mx = fmaxf(mx, sc);
      }
      float sm = 0.f;
#pragma unroll
      for (int ss = 0; ss < 18; ss++) {
        p_[ss] = expf(p_[ss] - mx);
        sm += p_[ss];
      }
      float inv = 1.f / sm;
#pragma unroll
      for (int d = 0; d < 5; d++) {
        float a = 0.f;
#pragma unroll
        for (int ss = 0; ss < 18; ss++)
          a = fmaf(p_[ss], v[ss * 28 + hh * 5 + d], a);
        av[(m * 18 + t) * 28 + hh * 5 + d] = a * inv;
      }
    }
  }
  __syncthreads();

  // ---- out-proj + residual (Wf row + av rows via float4) ----
  for (int idx = tid; idx < 450; idx += 256) {
    int t = idx / 25, j = idx % 25;
    const float4* wf4 = (const float4*)(sW + (3 * 25 + j) * 28);
    const float4* a04 = (const float4*)(av + (0 * 18 + t) * 28);
    const float4* a14 = (const float4*)(av + (1 * 18 + t) * 28);
    float s1 = sB[75 + j] + sbev[t * 28 + j];  // x1 residual = bev (feat1)
    float s2 = sB[75 + j] + sfv[t * 28 + j];   // x2 residual = fv
#pragma unroll
    for (int k = 0; k < 6; k++) {
      float4 wf = wf4[k], a0 = a04[k], a1 = a14[k];
      s1 = fmaf(a0.w, wf.w, fmaf(a0.z, wf.z, fmaf(a0.y, wf.y, fmaf(a0.x, wf.x, s1))));
      s2 = fmaf(a1.w, wf.w, fmaf(a1.z, wf.z, fmaf(a1.y, wf.y, fmaf(a1.x, wf.x, s2))));
    }
    {
      float wf = sW[(3 * 25 + j) * 28 + 24];
      s1 = fmaf(av[(0 * 18 + t) * 28 + 24], wf, s1);
      s2 = fmaf(av[(1 * 18 + t) * 28 + 24], wf, s2);
    }
    xx[(0 * 18 + t) * 28 + j] = s1;
    xx[(1 * 18 + t) * 28 + j] = s2;
  }
  __syncthreads();

  // ---- conv 36->18, 3x3, pad 1 on 5x5 ----
  for (int idx = tid; idx < 450; idx += 256) {
    int co = idx / 25, pos = idx % 25, pi = pos / 5, pj = pos % 5;
    float acc = conv_b[co];
    for (int ci = 0; ci < 36; ci++) {
      const float* xc = (ci < 18) ? &xx[(0 * 18 + ci) * 28] : &xx[(1 * 18 + (ci - 18)) * 28];
      const float* wp = conv_w + ((size_t)co * 36 + ci) * 9;
#pragma unroll
      for (int dh = 0; dh < 3; dh++) {
        int rr = pi + dh - 1;
        if ((unsigned)rr < 5u) {
#pragma unroll
          for (int dw = 0; dw < 3; dw++) {
            int cc = pj + dw - 1;
            if ((unsigned)cc < 5u) acc = fmaf(xc[rr * 5 + cc], wp[dh * 3 + dw], acc);
          }
        }
      }
    }
    hid[idx] = acc;
  }
  __syncthreads();

  // ---- fc1 (225 x 450) + relu: thread t owns output o=t; wt_fc1[i][o] coalesced;
  // hid via float4 (112 x b128 + 2 scalars) ----
  if (tid < 225) {
    int o = tid;
    float a0 = fc1_b[o], a1 = 0.f, a2 = 0.f, a3 = 0.f;
    const float4* h4 = (const float4*)hid;
    for (int k = 0; k < 112; k++) {  // elements 0..447
      float4 hv = h4[k];
      int i = k * 4;
      a0 = fmaf(hv.x, wt_fc1[(size_t)i * 256 + o], a0);
      a1 = fmaf(hv.y, wt_fc1[(size_t)(i + 1) * 256 + o], a1);
      a2 = fmaf(hv.z, wt_fc1[(size_t)(i + 2) * 256 + o], a2);
      a3 = fmaf(hv.w, wt_fc1[(size_t)(i + 3) * 256 + o], a3);
    }
    a0 = fmaf(hid[448], wt_fc1[(size_t)448 * 256 + o], a0);
    a1 = fmaf(hid[449], wt_fc1[(size_t)449 * 256 + o], a1);
    h1r[o] = fmaxf((a0 + a1) + (a2 + a3), 0.f);
  }
  __syncthreads();

  // ---- fc2 (3 x 225): wave w computes output w via shuffle reduction ----
  int wave = tid >> 6, lane = tid & 63;
  if (wave < 3) {
    const float* wr = fc2_w + (size_t)wave * 225;
    float p = 0.f;
#pragma unroll
    for (int k = 0; k < 4; k++) {
      int i = lane + k * 64;
      if (i < 225) p = fmaf(h1r[i], wr[i], p);
    }
#pragma unroll
    for (int m = 32; m >= 1; m >>= 1) p += __shfl_xor(p, m);
    if (lane == 0) lg[wave] = p + fc2_b[wave];
  }
  __syncthreads();

  // ---- argmax + softmax ----
  if (tid == 0) {
    float l0 = lg[0], l1 = lg[1], l2 = lg[2];
    int arg = 0;
    float bm = l0;
    if (l1 > bm) { arg = 1; bm = l1; }
    if (l2 > bm) { arg = 2; bm = l2; }
    float m = fmaxf(l0, fmaxf(l1, l2));
    float e0 = expf(l0 - m), e1 = expf(l1 - m), e2 = expf(l2 - m);
    float inv = 1.f / (e0 + e1 + e2);
    out[rid] = (float)(arg + 1);
    float* sc = out + 2048 + (size_t)rid * 3;
    sc[0] = e0 * inv;
    sc[1] = e1 * inv;
    sc[2] = e2 * inv;
  }
}

extern "C" void kernel_launch(void* const* d_in, const int* in_sizes, int n_in,
                              void* d_out, int out_size, void* d_ws, size_t ws_size,
                              hipStream_t stream) {
  const float* feat_fv = (const float*)d_in[0];
  const float* feat_bev = (const float*)d_in[1];
  const float* rois = (const float*)d_in[2];
  const float* fv_w1 = (const float*)d_in[3];
  const float* fv_b1 = (const float*)d_in[4];
  const float* fv_gamma = (const float*)d_in[5];
  const float* fv_beta = (const float*)d_in[6];
  const float* fv_mean = (const float*)d_in[7];
  const float* fv_var = (const float*)d_in[8];
  const float* fv_w2 = (const float*)d_in[9];
  const float* fv_b2 = (const float*)d_in[10];
  const float* bev_w1 = (const float*)d_in[11];
  const float* bev_b1 = (const float*)d_in[12];
  const float* bev_gamma = (const float*)d_in[13];
  const float* bev_beta = (const float*)d_in[14];
  const float* bev_mean = (const float*)d_in[15];
  const float* bev_var = (const float*)d_in[16];
  const float* bev_w2 = (const float*)d_in[17];
  const float* bev_b2 = (const float*)d_in[18];
  const float* Wq = (const float*)d_in[19];
  const float* bq = (const float*)d_in[20];
  const float* Wk = (const float*)d_in[21];
  const float* bk = (const float*)d_in[22];
  const float* Wv = (const float*)d_in[23];
  const float* bv = (const float*)d_in[24];
  const float* Wf = (const float*)d_in[25];
  const float* bf = (const float*)d_in[26];
  const float* conv_w = (const float*)d_in[27];
  const float* conv_b = (const float*)d_in[28];
  const float* fc1_w = (const float*)d_in[29];
  const float* fc1_b = (const float*)d_in[30];
  const float* fc2_w = (const float*)d_in[31];
  const float* fc2_b = (const float*)d_in[32];

  float* ws = (float*)d_ws;
  float* ffv = ws;                       // 2*18*64*512  = 1,179,648 floats
  float* fbev = ffv + 1179648;           // 2*18*200*176 = 1,267,200 floats
  float* wt_fv = fbev + 1267200;         // 128*9*18     = 20,736
  float* wt_bev = wt_fv + 20736;         // 512*9*18     = 82,944
  float* wt_fc1 = wt_bev + 82944;        // 450*256      = 115,200
  // total ~10.7 MB

  transpose_w_kernel<<<(18 * 128 * 9 + 255) / 256, 256, 0, stream>>>(fv_w1, wt_fv, 128);
  transpose_w_kernel<<<(18 * 512 * 9 + 255) / 256, 256, 0, stream>>>(bev_w1, wt_bev, 512);
  transpose_fc1_kernel<<<(225 * 450 + 255) / 256, 256, 0, stream>>>(fc1_w, wt_fc1);

  // merged pre: works [0,600) = bev row-pairs, [600,1112) = fv row-pairs; 512-thr blocks
  pre_merged_kernel<<<1112, 512, 0, stream>>>(
      feat_fv, wt_fv, fv_b1, fv_gamma, fv_beta, fv_mean, fv_var, fv_w2, fv_b2, ffv,
      feat_bev, wt_bev, bev_b1, bev_gamma, bev_beta, bev_mean, bev_var, bev_w2, bev_b2, fbev);

  classifier_kernel<<<2048, 256, 0, stream>>>(
      ffv, fbev, rois, Wq, bq, Wk, bk, Wv, bv, Wf, bf, conv_w, conv_b, wt_fc1,
      fc1_b, fc2_w, fc2_b, (float*)d_out);
}

// Round 17
// 376.001 us; speedup vs baseline: 1.1621x; 1.0397x over previous
//
#include <hip/hip_runtime.h>
#include <math.h>

// ---------------- weight transpose: w[18][C][3][3] -> wt[C][9][18] ----------------
__global__ void transpose_w_kernel(const float* __restrict__ w, float* __restrict__ wt, int C) {
  int idx = blockIdx.x * blockDim.x + threadIdx.x;
  int total = 18 * C * 9;
  if (idx >= total) return;
  int co = idx / (C * 9);
  int rem = idx % (C * 9);
  int ci = rem / 9;
  int tap = rem % 9;
  wt[(ci * 9 + tap) * 18 + co] = w[idx];
}

// ---------------- fc1 transpose: fc1_w[225][450] -> wt[450][256] (padded) ----------------
__global__ void transpose_fc1_kernel(const float* __restrict__ w, float* __restrict__ wt) {
  int idx = blockIdx.x * blockDim.x + threadIdx.x;
  if (idx >= 225 * 450) return;
  int o = idx / 450;
  int i = idx % 450;
  wt[i * 256 + o] = w[idx];
}

// ------------- merged fused conv3x3 + BN + relu + conv1x1 (fv + bev in one grid) ------------
// R11 VERBATIM — best measured (287us; total 376). Five configs (r6/r11/r13/r14/r16)
// all converge to >=287: VALU-cycles ~130us invariant, duty/occ ~0.78 invariant.
// Structurally converged; do not touch.
__global__ __launch_bounds__(256) void pre_merged_kernel(
    const float* __restrict__ xF, const float* __restrict__ wtF,
    const float* __restrict__ b1F, const float* __restrict__ gF,
    const float* __restrict__ beF, const float* __restrict__ muF,
    const float* __restrict__ vF, const float* __restrict__ w2F,
    const float* __restrict__ b2F, float* __restrict__ outF,
    const float* __restrict__ xB, const float* __restrict__ wtB,
    const float* __restrict__ b1B, const float* __restrict__ gB,
    const float* __restrict__ beB, const float* __restrict__ muB,
    const float* __restrict__ vB, const float* __restrict__ w2B,
    const float* __restrict__ b2B, float* __restrict__ outB) {
  int orig = blockIdx.x;
  int flat;
  if (orig < 1200) {                       // bev physical range; 1200 = 8*150
    flat = (orig & 7) * 150 + (orig >> 3); // XCD (orig&7) gets works [x*150, x*150+150)
  } else {                                 // fv physical range; 1024 = 8*128
    int j = orig - 1200;
    flat = 1200 + (j & 7) * 128 + (j >> 3);
  }

  const float *x, *wt, *b1, *gamma, *beta, *mean, *var, *w2, *b2;
  float* out;
  int H, W, cs, xt, h, b;
  if (flat < 1200) {  // bev: (3 xtiles, 200 h, 2 b), C=512, cs=128
    xt = flat % 3; h = (flat / 3) % 200; b = flat / 600;
    x = xB; wt = wtB; b1 = b1B; gamma = gB; beta = beB; mean = muB; var = vB;
    w2 = w2B; b2 = b2B; out = outB;
    H = 200; W = 176; cs = 128;
  } else {            // fv: (8 xtiles, 64 h, 2 b), C=128, cs=32
    int f = flat - 1200;
    xt = f & 7; h = (f >> 3) & 63; b = f >> 9;
    x = xF; wt = wtF; b1 = b1F; gamma = gF; beta = beF; mean = muF; var = vF;
    w2 = w2F; b2 = b2F; out = outF;
    H = 64; W = 512; cs = 32;
  }

  int tid = threadIdx.x;
  int pixel = tid & 63;
  int split = __builtin_amdgcn_readfirstlane(tid >> 6);  // wave-uniform -> SGPR
  int w = xt * 64 + pixel;
  bool active = (w < W);

  float acc[18];
#pragma unroll
  for (int i = 0; i < 18; i++) acc[i] = 0.f;

  const float* xb = x + (size_t)b * (cs * 4) * H * W;
  int ci0 = split * cs;
  for (int ci = 0; ci < cs; ci++) {
    const float* plane = xb + (size_t)(ci0 + ci) * H * W;
#pragma unroll
    for (int dh = 0; dh < 3; dh++) {
      int r = h + dh - 1;
      if ((unsigned)r < (unsigned)H) {
        const float* row = plane + (size_t)r * W;
        float v0 = (active && w >= 1) ? row[w - 1] : 0.f;
        float v1 = active ? row[w] : 0.f;
        float v2 = (active && w + 1 < W) ? row[w + 1] : 0.f;
        const float* wp = wt + ((size_t)(ci0 + ci) * 9 + dh * 3) * 18;  // scalar addr
#pragma unroll
        for (int co = 0; co < 18; co++) acc[co] = fmaf(v0, wp[co], acc[co]);
#pragma unroll
        for (int co = 0; co < 18; co++) acc[co] = fmaf(v1, wp[18 + co], acc[co]);
#pragma unroll
        for (int co = 0; co < 18; co++) acc[co] = fmaf(v2, wp[36 + co], acc[co]);
      }
    }
  }

  __shared__ float red[3][64][19];  // pad 19: conflict-free across pixel index
  if (split > 0) {
#pragma unroll
    for (int co = 0; co < 18; co++) red[split - 1][pixel][co] = acc[co];
  }
  __syncthreads();
  if (split == 0 && active) {
#pragma unroll
    for (int s = 0; s < 3; s++)
#pragma unroll
      for (int co = 0; co < 18; co++) acc[co] += red[s][pixel][co];
    float y[18];
#pragma unroll
    for (int co = 0; co < 18; co++) {
      float sc = gamma[co] / sqrtf(var[co] + 1e-3f);
      y[co] = fmaxf((acc[co] + b1[co] - mean[co]) * sc + beta[co], 0.f);
    }
    size_t obase = (size_t)b * 18 * H * W + (size_t)h * W + w;
#pragma unroll
    for (int co2 = 0; co2 < 18; co2++) {
      float s2 = b2[co2];
#pragma unroll
      for (int c = 0; c < 18; c++) s2 = fmaf(y[c], w2[co2 * 18 + c], s2);
      out[obase + (size_t)co2 * H * W] = s2;
    }
  }
}

// ------------- per-ROI classifier: one 256-thread block (4 waves) per ROI -------------
// r17: LDS aliasing. av held in REGISTERS then written into pr's dead vf/vb slots;
// xx -> dead qf/qb slots; hid -> dead kf slot (offset 504 floats, 16B-aligned).
// LDS 39.1KB -> 29.2KB => 4 -> 5 blocks/CU. Phase-order audit: every aliased region
// is written only after its last reader has passed a barrier.
__global__ __launch_bounds__(256) void classifier_kernel(
    const float* __restrict__ ffv, const float* __restrict__ fbev,
    const float* __restrict__ rois, const float* __restrict__ Wq,
    const float* __restrict__ bq, const float* __restrict__ Wk,
    const float* __restrict__ bk, const float* __restrict__ Wv,
    const float* __restrict__ bv, const float* __restrict__ Wf,
    const float* __restrict__ bf, const float* __restrict__ conv_w,
    const float* __restrict__ conv_b, const float* __restrict__ wt_fc1,
    const float* __restrict__ fc1_b, const float* __restrict__ fc2_w,
    const float* __restrict__ fc2_b, float* __restrict__ out) {
  int rid = blockIdx.x;
  int b = rid >> 10;
  int tid = threadIdx.x;

  __shared__ __align__(16) float sW[4 * 25 * 28];   // q|k|v|f rows, padded
  __shared__ float sB[100];                          // bq | bk | bv | bf
  __shared__ __align__(16) float sfv[18 * 28], sbev[18 * 28];
  __shared__ __align__(16) float pr[6 * 18 * 28];    // qf kf vf qb kb vb -> later aliased:
                                                     // pr[0]=x1, pr[1]=hid, pr[2]=av0,
                                                     // pr[3]=x2, pr[5]=av1
  __shared__ float h1r[226];
  __shared__ float lg[3];
  __shared__ int c_ixf[25], c_iyf[25], c_vf[25];
  __shared__ int c_ixb[25], c_iyb[25], c_vb[25];

  // ---- stage projection weights + biases into LDS (padded rows) ----
  for (int t = tid; t < 625; t += 256) {
    int j = t / 25, i = t % 25;
    sW[(0 * 25 + j) * 28 + i] = Wq[t];
    sW[(1 * 25 + j) * 28 + i] = Wk[t];
    sW[(2 * 25 + j) * 28 + i] = Wv[t];
    sW[(3 * 25 + j) * 28 + i] = Wf[t];
  }
  if (tid < 25) {
    sB[tid] = bq[tid];
    sB[25 + tid] = bk[tid];
    sB[50 + tid] = bv[tid];
    sB[75 + tid] = bf[tid];
  }

  // ---- box + grids coords (double to match np f64 ref) ----
  if (tid < 25) {
    const float* roi = rois + (size_t)rid * 7;
    double x0 = roi[0], y0 = roi[1], z0 = roi[2];
    double dx = roi[3], dy = roi[4], dz = roi[5], th = roi[6];
    double c = cos(th), s = sin(th);
    double half1 = (dy * c + dx * s) / 2.0;
    double half2 = (dy * s + dx * c) / 2.0;
    double bx1 = x0 - half1, bx2 = x0 + half1;
    double by1 = y0 - half2, by2 = y0 + half2;
    double bz1 = z0 - dz / 2.0, bz2 = z0 + dz / 2.0;
    int i = tid / 5, j = tid % 5;
    double ti = i * 0.25, tj = j * 0.25;
    // fv: feat (18, 64, 512)
    double gz = bz1 + ti * (bz2 - bz1);
    gz = (gz + 1.0) / 2.0;
    double gx = bx1 + tj * (bx2 - bx1);
    gx = (gx - 35.2) / 35.2;
    double ixf = rint((gz + 1.0) * 0.5 * 511.0);
    double iyf = rint((gx + 1.0) * 0.5 * 63.0);
    c_vf[tid] = (ixf >= 0.0) && (ixf <= 511.0) && (iyf >= 0.0) && (iyf <= 63.0);
    c_ixf[tid] = (int)fmin(fmax(ixf, 0.0), 511.0);
    c_iyf[tid] = (int)fmin(fmax(iyf, 0.0), 63.0);
    // bev: feat (18, 200, 176)
    double gzb = (by1 + ti * (by2 - by1)) / 40.0;
    double ixb = rint((gzb + 1.0) * 0.5 * 175.0);
    double iyb = rint((gx + 1.0) * 0.5 * 199.0);
    c_vb[tid] = (ixb >= 0.0) && (ixb <= 175.0) && (iyb >= 0.0) && (iyb <= 199.0);
    c_ixb[tid] = (int)fmin(fmax(ixb, 0.0), 175.0);
    c_iyb[tid] = (int)fmin(fmax(iyb, 0.0), 199.0);
  }
  __syncthreads();

  // ---- gather: 900 items (450 fv + 450 bev) across 256 threads ----
  {
    const float* fvb = ffv + (size_t)b * 18 * 64 * 512;
    const float* bvb = fbev + (size_t)b * 18 * 200 * 176;
    for (int item = tid; item < 900; item += 256) {
      if (item < 450) {
        int ch = item / 25, pos = item % 25;
        sfv[ch * 28 + pos] = c_vf[pos] ? fvb[((size_t)ch * 64 + c_iyf[pos]) * 512 + c_ixf[pos]] : 0.f;
      } else {
        int it = item - 450;
        int ch = it / 25, pos = it % 25;
        sbev[ch * 28 + pos] = c_vb[pos] ? bvb[((size_t)ch * 200 + c_iyb[pos]) * 176 + c_ixb[pos]] : 0.f;
      }
    }
  }
  __syncthreads();

  // ---- 6 projections: {fv,bev} x {Wq,Wk,Wv}, float4 LDS reads ----
  for (int idx = tid; idx < 450; idx += 256) {
    int t = idx / 25, j = idx % 25;
    const float4* xa4 = (const float4*)(sfv + t * 28);
    const float4* xb4 = (const float4*)(sbev + t * 28);
    const float4* wq4 = (const float4*)(sW + (0 * 25 + j) * 28);
    const float4* wk4 = (const float4*)(sW + (1 * 25 + j) * 28);
    const float4* wv4 = (const float4*)(sW + (2 * 25 + j) * 28);
    float aqf = sB[j], akf = sB[25 + j], avf = sB[50 + j];
    float aqb = sB[j], akb = sB[25 + j], avb = sB[50 + j];
#pragma unroll
    for (int k = 0; k < 6; k++) {  // elements 0..23
      float4 xa = xa4[k], xb = xb4[k];
      float4 wq = wq4[k], wk = wk4[k], wv = wv4[k];
      aqf = fmaf(xa.w, wq.w, fmaf(xa.z, wq.z, fmaf(xa.y, wq.y, fmaf(xa.x, wq.x, aqf))));
      akf = fmaf(xa.w, wk.w, fmaf(xa.z, wk.z, fmaf(xa.y, wk.y, fmaf(xa.x, wk.x, akf))));
      avf = fmaf(xa.w, wv.w, fmaf(xa.z, wv.z, fmaf(xa.y, wv.y, fmaf(xa.x, wv.x, avf))));
      aqb = fmaf(xb.w, wq.w, fmaf(xb.z, wq.z, fmaf(xb.y, wq.y, fmaf(xb.x, wq.x, aqb))));
      akb = fmaf(xb.w, wk.w, fmaf(xb.z, wk.z, fmaf(xb.y, wk.y, fmaf(xb.x, wk.x, akb))));
      avb = fmaf(xb.w, wv.w, fmaf(xb.z, wv.z, fmaf(xb.y, wv.y, fmaf(xb.x, wv.x, avb))));
    }
    {  // element 24
      float xa = sfv[t * 28 + 24], xb = sbev[t * 28 + 24];
      float wq = sW[(0 * 25 + j) * 28 + 24], wk = sW[(1 * 25 + j) * 28 + 24],
            wv = sW[(2 * 25 + j) * 28 + 24];
      aqf = fmaf(xa, wq, aqf); akf = fmaf(xa, wk, akf); avf = fmaf(xa, wv, avf);
      aqb = fmaf(xb, wq, aqb); akb = fmaf(xb, wk, akb); avb = fmaf(xb, wv, avb);
    }
    pr[(0 * 18 + t) * 28 + j] = aqf;
    pr[(1 * 18 + t) * 28 + j] = akf;
    pr[(2 * 18 + t) * 28 + j] = avf;
    pr[(3 * 18 + t) * 28 + j] = aqb;
    pr[(4 * 18 + t) * 28 + j] = akb;
    pr[(5 * 18 + t) * 28 + j] = avb;
  }
  __syncthreads();

  // ---- attention: row = (head, token), 90 rows; result kept in REGISTERS ----
  const float rs5 = 0.44721359549995793f;  // 1/sqrt(5)
  float avreg[2][5];
  int hh_a = tid / 18, t_a = tid % 18;
  if (tid < 90) {
#pragma unroll
    for (int m = 0; m < 2; m++) {
      const float* q = pr + (m == 0 ? 0 : 3) * 504;
      const float* k = pr + (m == 0 ? 4 : 1) * 504;
      const float* v = pr + (m == 0 ? 2 : 5) * 504;
      float p_[18];
      float mx = -1e30f;
#pragma unroll
      for (int ss = 0; ss < 18; ss++) {
        float sc = 0.f;
#pragma unroll
        for (int d = 0; d < 5; d++)
          sc = fmaf(q[t_a * 28 + hh_a * 5 + d], k[ss * 28 + hh_a * 5 + d], sc);
        sc *= rs5;
        p_[ss] = sc;
        mx = fmaxf(mx, sc);
      }
      float sm = 0.f;
#pragma unroll
      for (int ss = 0; ss < 18; ss++) {
        p_[ss] = expf(p_[ss] - mx);
        sm += p_[ss];
      }
      float inv = 1.f / sm;
#pragma unroll
      for (int d = 0; d < 5; d++) {
        float a = 0.f;
#pragma unroll
        for (int ss = 0; ss < 18; ss++)
          a = fmaf(p_[ss], v[ss * 28 + hh_a * 5 + d], a);
        avreg[m][d] = a * inv;
      }
    }
  }
  __syncthreads();  // all pr reads (q,k,v) complete
  if (tid < 90) {
#pragma unroll
    for (int m = 0; m < 2; m++)
#pragma unroll
      for (int d = 0; d < 5; d++)
        pr[(m == 0 ? 2 : 5) * 504 + t_a * 28 + hh_a * 5 + d] = avreg[m][d];  // av -> vf/vb slots
  }
  __syncthreads();

  // ---- out-proj + residual: av from pr[2]/pr[5]; x1 -> pr[0], x2 -> pr[3] ----
  for (int idx = tid; idx < 450; idx += 256) {
    int t = idx / 25, j = idx % 25;
    const float4* wf4 = (const float4*)(sW + (3 * 25 + j) * 28);
    const float4* a04 = (const float4*)(pr + 2 * 504 + t * 28);
    const float4* a14 = (const float4*)(pr + 5 * 504 + t * 28);
    float s1 = sB[75 + j] + sbev[t * 28 + j];  // x1 residual = bev (feat1)
    float s2 = sB[75 + j] + sfv[t * 28 + j];   // x2 residual = fv
#pragma unroll
    for (int k = 0; k < 6; k++) {
      float4 wf = wf4[k], a0 = a04[k], a1 = a14[k];
      s1 = fmaf(a0.w, wf.w, fmaf(a0.z, wf.z, fmaf(a0.y, wf.y, fmaf(a0.x, wf.x, s1))));
      s2 = fmaf(a1.w, wf.w, fmaf(a1.z, wf.z, fmaf(a1.y, wf.y, fmaf(a1.x, wf.x, s2))));
    }
    {
      float wf = sW[(3 * 25 + j) * 28 + 24];
      s1 = fmaf(pr[2 * 504 + t * 28 + 24], wf, s1);
      s2 = fmaf(pr[5 * 504 + t * 28 + 24], wf, s2);
    }
    pr[0 * 504 + t * 28 + j] = s1;  // x1 -> qf slot (dead after attention)
    pr[3 * 504 + t * 28 + j] = s2;  // x2 -> qb slot
  }
  __syncthreads();

  // ---- conv 36->18, 3x3, pad 1 on 5x5: x from pr[0]/pr[3]; hid -> pr[1] ----
  for (int idx = tid; idx < 450; idx += 256) {
    int co = idx / 25, pos = idx % 25, pi = pos / 5, pj = pos % 5;
    float acc = conv_b[co];
    for (int ci = 0; ci < 36; ci++) {
      const float* xc = (ci < 18) ? (pr + 0 * 504 + ci * 28) : (pr + 3 * 504 + (ci - 18) * 28);
      const float* wp = conv_w + ((size_t)co * 36 + ci) * 9;
#pragma unroll
      for (int dh = 0; dh < 3; dh++) {
        int rr = pi + dh - 1;
        if ((unsigned)rr < 5u) {
#pragma unroll
          for (int dw = 0; dw < 3; dw++) {
            int cc = pj + dw - 1;
            if ((unsigned)cc < 5u) acc = fmaf(xc[rr * 5 + cc], wp[dh * 3 + dw], acc);
          }
        }
      }
    }
    pr[504 + idx] = acc;  // hid -> kf slot (dead); base 504*4B = 2016B, 16B-aligned
  }
  __syncthreads();

  // ---- fc1 (225 x 450) + relu: hid from pr+504 via float4; wt_fc1[i][o] coalesced ----
  if (tid < 225) {
    int o = tid;
    float a0 = fc1_b[o], a1 = 0.f, a2 = 0.f, a3 = 0.f;
    const float4* h4 = (const float4*)(pr + 504);
    for (int k = 0; k < 112; k++) {  // elements 0..447
      float4 hv = h4[k];
      int i = k * 4;
      a0 = fmaf(hv.x, wt_fc1[(size_t)i * 256 + o], a0);
      a1 = fmaf(hv.y, wt_fc1[(size_t)(i + 1) * 256 + o], a1);
      a2 = fmaf(hv.z, wt_fc1[(size_t)(i + 2) * 256 + o], a2);
      a3 = fmaf(hv.w, wt_fc1[(size_t)(i + 3) * 256 + o], a3);
    }
    a0 = fmaf(pr[504 + 448], wt_fc1[(size_t)448 * 256 + o], a0);
    a1 = fmaf(pr[504 + 449], wt_fc1[(size_t)449 * 256 + o], a1);
    h1r[o] = fmaxf((a0 + a1) + (a2 + a3), 0.f);
  }
  __syncthreads();

  // ---- fc2 (3 x 225): wave w computes output w via shuffle reduction ----
  int wave = tid >> 6, lane = tid & 63;
  if (wave < 3) {
    const float* wr = fc2_w + (size_t)wave * 225;
    float p = 0.f;
#pragma unroll
    for (int k = 0; k < 4; k++) {
      int i = lane + k * 64;
      if (i < 225) p = fmaf(h1r[i], wr[i], p);
    }
#pragma unroll
    for (int m = 32; m >= 1; m >>= 1) p += __shfl_xor(p, m);
    if (lane == 0) lg[wave] = p + fc2_b[wave];
  }
  __syncthreads();

  // ---- argmax + softmax ----
  if (tid == 0) {
    float l0 = lg[0], l1 = lg[1], l2 = lg[2];
    int arg = 0;
    float bm = l0;
    if (l1 > bm) { arg = 1; bm = l1; }
    if (l2 > bm) { arg = 2; bm = l2; }
    float m = fmaxf(l0, fmaxf(l1, l2));
    float e0 = expf(l0 - m), e1 = expf(l1 - m), e2 = expf(l2 - m);
    float inv = 1.f / (e0 + e1 + e2);
    out[rid] = (float)(arg + 1);
    float* sc = out + 2048 + (size_t)rid * 3;
    sc[0] = e0 * inv;
    sc[1] = e1 * inv;
    sc[2] = e2 * inv;
  }
}

extern "C" void kernel_launch(void* const* d_in, const int* in_sizes, int n_in,
                              void* d_out, int out_size, void* d_ws, size_t ws_size,
                              hipStream_t stream) {
  const float* feat_fv = (const float*)d_in[0];
  const float* feat_bev = (const float*)d_in[1];
  const float* rois = (const float*)d_in[2];
  const float* fv_w1 = (const float*)d_in[3];
  const float* fv_b1 = (const float*)d_in[4];
  const float* fv_gamma = (const float*)d_in[5];
  const float* fv_beta = (const float*)d_in[6];
  const float* fv_mean = (const float*)d_in[7];
  const float* fv_var = (const float*)d_in[8];
  const float* fv_w2 = (const float*)d_in[9];
  const float* fv_b2 = (const float*)d_in[10];
  const float* bev_w1 = (const float*)d_in[11];
  const float* bev_b1 = (const float*)d_in[12];
  const float* bev_gamma = (const float*)d_in[13];
  const float* bev_beta = (const float*)d_in[14];
  const float* bev_mean = (const float*)d_in[15];
  const float* bev_var = (const float*)d_in[16];
  const float* bev_w2 = (const float*)d_in[17];
  const float* bev_b2 = (const float*)d_in[18];
  const float* Wq = (const float*)d_in[19];
  const float* bq = (const float*)d_in[20];
  const float* Wk = (const float*)d_in[21];
  const float* bk = (const float*)d_in[22];
  const float* Wv = (const float*)d_in[23];
  const float* bv = (const float*)d_in[24];
  const float* Wf = (const float*)d_in[25];
  const float* bf = (const float*)d_in[26];
  const float* conv_w = (const float*)d_in[27];
  const float* conv_b = (const float*)d_in[28];
  const float* fc1_w = (const float*)d_in[29];
  const float* fc1_b = (const float*)d_in[30];
  const float* fc2_w = (const float*)d_in[31];
  const float* fc2_b = (const float*)d_in[32];

  float* ws = (float*)d_ws;
  float* ffv = ws;                       // 2*18*64*512  = 1,179,648 floats
  float* fbev = ffv + 1179648;           // 2*18*200*176 = 1,267,200 floats
  float* wt_fv = fbev + 1267200;         // 128*9*18     = 20,736
  float* wt_bev = wt_fv + 20736;         // 512*9*18     = 82,944
  float* wt_fc1 = wt_bev + 82944;        // 450*256      = 115,200
  // total ~10.7 MB

  transpose_w_kernel<<<(18 * 128 * 9 + 255) / 256, 256, 0, stream>>>(fv_w1, wt_fv, 128);
  transpose_w_kernel<<<(18 * 512 * 9 + 255) / 256, 256, 0, stream>>>(bev_w1, wt_bev, 512);
  transpose_fc1_kernel<<<(225 * 450 + 255) / 256, 256, 0, stream>>>(fc1_w, wt_fc1);

  // merged pre: works [0,1200) = bev, [1200,2224) = fv; physical->work swizzle inside
  pre_merged_kernel<<<2224, 256, 0, stream>>>(
      feat_fv, wt_fv, fv_b1, fv_gamma, fv_beta, fv_mean, fv_var, fv_w2, fv_b2, ffv,
      feat_bev, wt_bev, bev_b1, bev_gamma, bev_beta, bev_mean, bev_var, bev_w2, bev_b2, fbev);

  classifier_kernel<<<2048, 256, 0, stream>>>(
      ffv, fbev, rois, Wq, bq, Wk, bk, Wv, bv, Wf, bf, conv_w, conv_b, wt_fc1,
      fc1_b, fc2_w, fc2_b, (float*)d_out);
}